// Round 1
// baseline (771.515 us; speedup 1.0000x reference)
//
#include <hip/hip_runtime.h>

#define N_NODES 100000

// ---------------------------------------------------------------------------
// Degree accumulation: deg[dst] += 1 per edge (float atomics; avg degree 16)
// ---------------------------------------------------------------------------
__global__ __launch_bounds__(256) void deg_kernel(const int* __restrict__ dst, int E,
                                                  float* __restrict__ deg) {
    int i = blockIdx.x * 256 + threadIdx.x;
    if (i < E) atomicAdd(&deg[dst[i]], 1.0f);
}

// deg -> rsqrt(deg + 1)  (self-loop included), in place
__global__ __launch_bounds__(256) void dinv_kernel(float* __restrict__ deg, int n) {
    int i = blockIdx.x * 256 + threadIdx.x;
    if (i < n) deg[i] = rsqrtf(deg[i] + 1.0f);
}

// ---------------------------------------------------------------------------
// GEMM1: h1[N,64] = x[N,128] @ W1[128,64];  agg1 = h1 * dinv^2 (self-loop init)
// Block: 256 threads, 16 rows. W1 (32KB) + x-tile (8KB) staged in LDS.
// Thread (j = tid&63, rg = tid>>6) computes rows rg, rg+4, rg+8, rg+12.
// LDS patterns: W row read by consecutive j -> conflict-free; xs read is a
// wave-broadcast (all 64 lanes of a wave share rg).
// ---------------------------------------------------------------------------
__global__ __launch_bounds__(256) void gemm1_kernel(
    const float* __restrict__ x, const float* __restrict__ W,
    const float* __restrict__ dinv,
    float* __restrict__ h1, float* __restrict__ agg1, int N) {
    __shared__ float Ws[128 * 64];
    __shared__ float xs[16 * 128];
    int tid = threadIdx.x;
    for (int i = tid; i < 128 * 64; i += 256) Ws[i] = W[i];
    int row0 = blockIdx.x * 16;
    for (int i = tid; i < 16 * 128; i += 256) {
        int r = i >> 7, c = i & 127;
        int gr = row0 + r;
        xs[i] = (gr < N) ? x[(size_t)gr * 128 + c] : 0.0f;
    }
    __syncthreads();
    int j = tid & 63;
    int rg = tid >> 6;  // 0..3
    float acc0 = 0.f, acc1 = 0.f, acc2 = 0.f, acc3 = 0.f;
#pragma unroll 8
    for (int k = 0; k < 128; ++k) {
        float w = Ws[k * 64 + j];
        acc0 += xs[(rg + 0) * 128 + k] * w;
        acc1 += xs[(rg + 4) * 128 + k] * w;
        acc2 += xs[(rg + 8) * 128 + k] * w;
        acc3 += xs[(rg + 12) * 128 + k] * w;
    }
    float accs[4] = {acc0, acc1, acc2, acc3};
#pragma unroll
    for (int i = 0; i < 4; ++i) {
        int r = row0 + rg + i * 4;
        if (r < N) {
            float v = accs[i];
            float di = dinv[r];
            h1[(size_t)r * 64 + j] = v;
            agg1[(size_t)r * 64 + j] = v * di * di;
        }
    }
}

// ---------------------------------------------------------------------------
// Scatter layer 1: thread = (edge, feature j of 64).
// agg1[dst*64+j] += h1[src*64+j] * dinv[src]*dinv[dst]
// Per wave: one edge -> 256B coalesced gather + 64 contiguous atomics.
// ---------------------------------------------------------------------------
__global__ __launch_bounds__(256) void scatter1_kernel(
    const int* __restrict__ ei, int E,
    const float* __restrict__ dinv,
    const float* __restrict__ h1,
    float* __restrict__ agg1) {
    int gid = blockIdx.x * 256 + threadIdx.x;  // < E*64 = 102.4M, fits int32
    int e = gid >> 6;
    int j = gid & 63;
    if (e >= E) return;
    int s = ei[e];
    int d = ei[E + e];
    float norm = dinv[s] * dinv[d];
    atomicAdd(&agg1[(size_t)d * 64 + j], h1[(size_t)s * 64 + j] * norm);
}

// h_relu = relu(agg1 + b1), in place
__global__ __launch_bounds__(256) void finish1_kernel(float* __restrict__ agg1,
                                                      const float* __restrict__ b1,
                                                      int total) {
    int i = blockIdx.x * 256 + threadIdx.x;
    if (i < total) {
        float v = agg1[i] + b1[i & 63];
        agg1[i] = v > 0.f ? v : 0.f;
    }
}

// ---------------------------------------------------------------------------
// GEMM2: h2[N,32] = h_relu[N,64] @ W2[64,32];  out = h2*dinv^2 + b2 (init)
// Block: 256 threads, 32 rows. W2 (8KB) + x-tile (8KB) in LDS.
// ---------------------------------------------------------------------------
__global__ __launch_bounds__(256) void gemm2_kernel(
    const float* __restrict__ h, const float* __restrict__ W,
    const float* __restrict__ dinv, const float* __restrict__ b2,
    float* __restrict__ h2, float* __restrict__ out, int N) {
    __shared__ float Ws[64 * 32];
    __shared__ float xs[32 * 64];
    int tid = threadIdx.x;
    for (int i = tid; i < 64 * 32; i += 256) Ws[i] = W[i];
    int row0 = blockIdx.x * 32;
    for (int i = tid; i < 32 * 64; i += 256) {
        int r = i >> 6, c = i & 63;
        int gr = row0 + r;
        xs[i] = (gr < N) ? h[(size_t)gr * 64 + c] : 0.0f;
    }
    __syncthreads();
    int j = tid & 31;
    int rg = tid >> 5;  // 0..7
    float acc0 = 0.f, acc1 = 0.f, acc2 = 0.f, acc3 = 0.f;
#pragma unroll 8
    for (int k = 0; k < 64; ++k) {
        float w = Ws[k * 32 + j];
        acc0 += xs[(rg + 0) * 64 + k] * w;
        acc1 += xs[(rg + 8) * 64 + k] * w;
        acc2 += xs[(rg + 16) * 64 + k] * w;
        acc3 += xs[(rg + 24) * 64 + k] * w;
    }
    float accs[4] = {acc0, acc1, acc2, acc3};
#pragma unroll
    for (int i = 0; i < 4; ++i) {
        int r = row0 + rg + i * 8;
        if (r < N) {
            float v = accs[i];
            float di = dinv[r];
            h2[(size_t)r * 32 + j] = v;
            out[(size_t)r * 32 + j] = v * di * di + b2[j];
        }
    }
}

// Scatter layer 2: thread = (edge, feature j of 32), accumulate into d_out.
__global__ __launch_bounds__(256) void scatter2_kernel(
    const int* __restrict__ ei, int E,
    const float* __restrict__ dinv,
    const float* __restrict__ h2,
    float* __restrict__ out) {
    int gid = blockIdx.x * 256 + threadIdx.x;  // < E*32 = 51.2M
    int e = gid >> 5;
    int j = gid & 31;
    if (e >= E) return;
    int s = ei[e];
    int d = ei[E + e];
    float norm = dinv[s] * dinv[d];
    atomicAdd(&out[(size_t)d * 32 + j], h2[(size_t)s * 32 + j] * norm);
}

extern "C" void kernel_launch(void* const* d_in, const int* in_sizes, int n_in,
                              void* d_out, int out_size, void* d_ws, size_t ws_size,
                              hipStream_t stream) {
    const float* x  = (const float*)d_in[0];
    const int*   ei = (const int*)d_in[1];
    const float* W1 = (const float*)d_in[2];
    const float* b1 = (const float*)d_in[3];
    const float* W2 = (const float*)d_in[4];
    const float* b2 = (const float*)d_in[5];
    float* out = (float*)d_out;

    const int N = N_NODES;
    const int E = in_sizes[1] / 2;

    // Workspace layout (floats): deg[N] | h1[N*64] | agg1[N*64]
    float* deg  = (float*)d_ws;
    float* h1   = deg + N;
    float* agg1 = h1 + (size_t)N * 64;
    float* h2   = h1;  // h1 dead after scatter1; reuse for h2 (N*32 <= N*64)

    hipMemsetAsync(deg, 0, (size_t)N * sizeof(float), stream);

    deg_kernel<<<(E + 255) / 256, 256, 0, stream>>>(ei + E, E, deg);
    dinv_kernel<<<(N + 255) / 256, 256, 0, stream>>>(deg, N);

    gemm1_kernel<<<(N + 15) / 16, 256, 0, stream>>>(x, W1, deg, h1, agg1, N);
    {
        long long t = (long long)E * 64;
        scatter1_kernel<<<(int)((t + 255) / 256), 256, 0, stream>>>(ei, E, deg, h1, agg1);
    }
    finish1_kernel<<<(N * 64 + 255) / 256, 256, 0, stream>>>(agg1, b1, N * 64);

    gemm2_kernel<<<(N + 31) / 32, 256, 0, stream>>>(agg1, W2, deg, b2, h2, out, N);
    {
        long long t = (long long)E * 32;
        scatter2_kernel<<<(int)((t + 255) / 256), 256, 0, stream>>>(ei, E, deg, h2, out);
    }
}

// Round 2
// 486.640 us; speedup vs baseline: 1.5854x; 1.5854x over previous
//
#include <hip/hip_runtime.h>

#define N_NODES 100000

// ============================ CSR construction =============================

// deg[dst] += 1 per edge (uint atomics on 400KB array -> L2-resident, fast)
__global__ __launch_bounds__(256) void hist_kernel(const int* __restrict__ dst, int E,
                                                   unsigned int* __restrict__ deg) {
    int i = blockIdx.x * 256 + threadIdx.x;
    if (i < E) atomicAdd(&deg[dst[i]], 1u);
}

__global__ __launch_bounds__(256) void dinv_kernel(const unsigned int* __restrict__ deg,
                                                   float* __restrict__ dinv, int n) {
    int i = blockIdx.x * 256 + threadIdx.x;
    if (i < n) dinv[i] = rsqrtf((float)deg[i] + 1.0f);
}

// scanA: block = 1024-element chunk -> chunk total
__global__ __launch_bounds__(256) void scanA_kernel(const unsigned int* __restrict__ deg,
                                                    int n, unsigned int* __restrict__ totals) {
    __shared__ unsigned int s[256];
    int t = threadIdx.x;
    int base = blockIdx.x * 1024 + t * 4;
    unsigned int sum = 0;
#pragma unroll
    for (int k = 0; k < 4; ++k) { int i = base + k; if (i < n) sum += deg[i]; }
    s[t] = sum; __syncthreads();
    for (int off = 128; off > 0; off >>= 1) {
        if (t < off) s[t] += s[t + off];
        __syncthreads();
    }
    if (t == 0) totals[blockIdx.x] = s[0];
}

// scanB: exclusive scan of chunk totals (<=128 chunks), single block
__global__ __launch_bounds__(128) void scanB_kernel(const unsigned int* __restrict__ totals,
                                                    int nblk, unsigned int* __restrict__ offsets,
                                                    int* __restrict__ row_start, int n, int E) {
    __shared__ unsigned int s[128];
    int t = threadIdx.x;
    unsigned int v = (t < nblk) ? totals[t] : 0u;
    s[t] = v; __syncthreads();
    for (int off = 1; off < 128; off <<= 1) {
        unsigned int x = s[t];
        unsigned int y = (t >= off) ? s[t - off] : 0u;
        __syncthreads();
        s[t] = x + y;
        __syncthreads();
    }
    if (t < nblk) offsets[t] = s[t] - v;  // exclusive
    if (t == 0) row_start[n] = E;
}

// scanC: per-element exclusive scan -> row_start + cursor (cursor = working copy)
__global__ __launch_bounds__(256) void scanC_kernel(const unsigned int* __restrict__ deg,
                                                    const unsigned int* __restrict__ offsets,
                                                    int n, int* __restrict__ row_start,
                                                    int* __restrict__ cursor) {
    __shared__ unsigned int s[256];
    int t = threadIdx.x;
    int base = blockIdx.x * 1024 + t * 4;
    unsigned int v[4];
    unsigned int sum = 0;
#pragma unroll
    for (int k = 0; k < 4; ++k) { int i = base + k; v[k] = (i < n) ? deg[i] : 0u; sum += v[k]; }
    s[t] = sum; __syncthreads();
    for (int off = 1; off < 256; off <<= 1) {   // inclusive Hillis-Steele
        unsigned int x = s[t];
        unsigned int y = (t >= off) ? s[t - off] : 0u;
        __syncthreads();
        s[t] = x + y;
        __syncthreads();
    }
    unsigned int excl = s[t] - sum + offsets[blockIdx.x];
#pragma unroll
    for (int k = 0; k < 4; ++k) {
        int i = base + k;
        if (i < n) { row_start[i] = (int)excl; cursor[i] = (int)excl; }
        excl += v[k];
    }
}

// fill: csr[slot] = (src, norm) grouped by dst. int atomics on 400KB cursor.
__global__ __launch_bounds__(256) void fill_kernel(const int* __restrict__ ei, int E,
                                                   const float* __restrict__ dinv,
                                                   int* __restrict__ cursor,
                                                   int2* __restrict__ csr) {
    int e = blockIdx.x * 256 + threadIdx.x;
    if (e >= E) return;
    int s = ei[e];
    int d = ei[E + e];
    int idx = atomicAdd(&cursor[d], 1);
    int2 ent; ent.x = s; ent.y = __float_as_int(dinv[s] * dinv[d]);
    csr[idx] = ent;
}

// ============================ GEMM1: h1 = x @ W1 ===========================
// Block: 256 threads, 16 rows. W1 (32KB) + x-tile (8KB) in LDS.
__global__ __launch_bounds__(256) void gemm1_kernel(
    const float* __restrict__ x, const float* __restrict__ W,
    float* __restrict__ h1, int N) {
    __shared__ float Ws[128 * 64];
    __shared__ float xs[16 * 128];
    int tid = threadIdx.x;
    for (int i = tid; i < 128 * 64; i += 256) Ws[i] = W[i];
    int row0 = blockIdx.x * 16;
    for (int i = tid; i < 16 * 128; i += 256) {
        int r = i >> 7, c = i & 127;
        int gr = row0 + r;
        xs[i] = (gr < N) ? x[(size_t)gr * 128 + c] : 0.0f;
    }
    __syncthreads();
    int j = tid & 63;
    int rg = tid >> 6;
    float acc0 = 0.f, acc1 = 0.f, acc2 = 0.f, acc3 = 0.f;
#pragma unroll 8
    for (int k = 0; k < 128; ++k) {
        float w = Ws[k * 64 + j];
        acc0 += xs[(rg + 0) * 128 + k] * w;
        acc1 += xs[(rg + 4) * 128 + k] * w;
        acc2 += xs[(rg + 8) * 128 + k] * w;
        acc3 += xs[(rg + 12) * 128 + k] * w;
    }
    float accs[4] = {acc0, acc1, acc2, acc3};
#pragma unroll
    for (int i = 0; i < 4; ++i) {
        int r = row0 + rg + i * 4;
        if (r < N) h1[(size_t)r * 64 + j] = accs[i];
    }
}

// ================= Aggregation 1 (+bias+relu) fused with GEMM2 =============
// One wave per dst node. Lane j accumulates feature j over in-edges (gather,
// no atomics). Then h_relu row staged in LDS, 32 MACs/lane + shfl_xor gives
// h2[d] = relu(agg+b1) @ W2 without materializing h_relu globally.
__global__ __launch_bounds__(256) void agg1_kernel(
    const float* __restrict__ h1, const int2* __restrict__ csr,
    const int* __restrict__ row_start, const float* __restrict__ dinv,
    const float* __restrict__ b1, const float* __restrict__ W2,
    float* __restrict__ h2, int N) {
    __shared__ float W2s[64 * 32];
    __shared__ float hr[4][64];
    int tid = threadIdx.x;
    for (int i = tid; i < 64 * 32; i += 256) W2s[i] = W2[i];
    __syncthreads();
    int wave = tid >> 6, j = tid & 63;
    int d = blockIdx.x * 4 + wave;
    if (d >= N) return;  // no barriers after this point
    float di = dinv[d];
    float acc = h1[(size_t)d * 64 + j] * di * di;   // self-loop
    int beg = row_start[d], end = row_start[d + 1];
    int e = beg;
    for (; e + 1 < end; e += 2) {                   // unroll-2: 2 gathers in flight
        int2 c0 = csr[e], c1 = csr[e + 1];
        float v0 = h1[(size_t)c0.x * 64 + j];
        float v1 = h1[(size_t)c1.x * 64 + j];
        acc += v0 * __int_as_float(c0.y);
        acc += v1 * __int_as_float(c1.y);
    }
    if (e < end) {
        int2 c0 = csr[e];
        acc += h1[(size_t)c0.x * 64 + j] * __int_as_float(c0.y);
    }
    float h = acc + b1[j];
    h = h > 0.f ? h : 0.f;
    hr[wave][j] = h;        // intra-wave LDS round-trip, no barrier needed
    // h2[d,c] = sum_j hr[j] * W2[j,c]; lane l: c = l&31, half j-range by l>>5
    int c = j & 31;
    int j0 = (j >> 5) * 32;
    const float* hrw = hr[wave];
    float p = 0.f;
#pragma unroll 8
    for (int k = 0; k < 32; ++k)
        p += hrw[j0 + k] * W2s[(j0 + k) * 32 + c];
    p += __shfl_xor(p, 32, 64);
    if (j < 32) h2[(size_t)d * 32 + c] = p;
}

// ===================== Aggregation 2 -> out (final layer) ==================
// Half-wave (32 lanes) per dst node; lane j = feature. out fully overwritten.
__global__ __launch_bounds__(256) void agg2_kernel(
    const float* __restrict__ h2, const int2* __restrict__ csr,
    const int* __restrict__ row_start, const float* __restrict__ dinv,
    const float* __restrict__ b2, float* __restrict__ out, int N) {
    int tid = blockIdx.x * 256 + threadIdx.x;
    int d = tid >> 5;
    int j = tid & 31;
    if (d >= N) return;
    float di = dinv[d];
    float acc = h2[(size_t)d * 32 + j] * di * di + b2[j];  // self-loop + bias
    int beg = row_start[d], end = row_start[d + 1];
    int e = beg;
    for (; e + 1 < end; e += 2) {
        int2 c0 = csr[e], c1 = csr[e + 1];
        acc += h2[(size_t)c0.x * 32 + j] * __int_as_float(c0.y);
        acc += h2[(size_t)c1.x * 32 + j] * __int_as_float(c1.y);
    }
    if (e < end) {
        int2 c0 = csr[e];
        acc += h2[(size_t)c0.x * 32 + j] * __int_as_float(c0.y);
    }
    out[(size_t)d * 32 + j] = acc;
}

extern "C" void kernel_launch(void* const* d_in, const int* in_sizes, int n_in,
                              void* d_out, int out_size, void* d_ws, size_t ws_size,
                              hipStream_t stream) {
    const float* x  = (const float*)d_in[0];
    const int*   ei = (const int*)d_in[1];
    const float* W1 = (const float*)d_in[2];
    const float* b1 = (const float*)d_in[3];
    const float* W2 = (const float*)d_in[4];
    const float* b2 = (const float*)d_in[5];
    float* out = (float*)d_out;

    const int N = N_NODES;
    const int E = in_sizes[1] / 2;
    const int NBLK = (N + 1023) / 1024;  // 98

    // Workspace layout (8B-aligned first): csr[E] int2 | h1[N*64] f32 |
    // h2[N*32] f32 | deg[N] u32 | dinv[N] f32 | row_start[N+1] int |
    // cursor[N] int | totals[128] | offsets[128]   (~52.9 MB total)
    char* p = (char*)d_ws;
    int2* csr = (int2*)p;                 p += (size_t)E * 8;
    float* h1 = (float*)p;                p += (size_t)N * 64 * 4;
    float* h2 = (float*)p;                p += (size_t)N * 32 * 4;
    unsigned int* deg = (unsigned int*)p; p += (size_t)N * 4;
    float* dinv = (float*)p;              p += (size_t)N * 4;
    int* row_start = (int*)p;             p += (size_t)(N + 1) * 4;
    int* cursor = (int*)p;                p += (size_t)N * 4;
    unsigned int* totals = (unsigned int*)p;  p += 128 * 4;
    unsigned int* offsets = (unsigned int*)p;

    hipMemsetAsync(deg, 0, (size_t)N * sizeof(unsigned int), stream);

    hist_kernel<<<(E + 255) / 256, 256, 0, stream>>>(ei + E, E, deg);
    dinv_kernel<<<(N + 255) / 256, 256, 0, stream>>>(deg, dinv, N);
    scanA_kernel<<<NBLK, 256, 0, stream>>>(deg, N, totals);
    scanB_kernel<<<1, 128, 0, stream>>>(totals, NBLK, offsets, row_start, N, E);
    scanC_kernel<<<NBLK, 256, 0, stream>>>(deg, offsets, N, row_start, cursor);
    fill_kernel<<<(E + 255) / 256, 256, 0, stream>>>(ei, E, dinv, cursor, csr);

    gemm1_kernel<<<(N + 15) / 16, 256, 0, stream>>>(x, W1, h1, N);
    agg1_kernel<<<(N + 3) / 4, 256, 0, stream>>>(h1, csr, row_start, dinv, b1, W2, h2, N);
    agg2_kernel<<<(N * 32 + 255) / 256, 256, 0, stream>>>(h2, csr, row_start, dinv, b2, out, N);
}

// Round 3
// 379.739 us; speedup vs baseline: 2.0317x; 1.2815x over previous
//
#include <hip/hip_runtime.h>

#define N_NODES 100000

// ---- bf16 helpers (manual, RNE) -------------------------------------------
__device__ __forceinline__ unsigned short f2bf_rn(float f) {
    unsigned int b = __float_as_uint(f);
    b += 0x7fffu + ((b >> 16) & 1u);
    return (unsigned short)(b >> 16);
}
__device__ __forceinline__ float bf_lo(unsigned int u) { return __uint_as_float(u << 16); }
__device__ __forceinline__ float bf_hi(unsigned int u) { return __uint_as_float(u & 0xffff0000u); }

// ============================ CSR construction =============================

__global__ __launch_bounds__(256) void hist_kernel(const int* __restrict__ dst, int E,
                                                   unsigned int* __restrict__ deg) {
    int i = blockIdx.x * 256 + threadIdx.x;
    if (i < E) atomicAdd(&deg[dst[i]], 1u);
}

__global__ __launch_bounds__(256) void dinv_kernel(const unsigned int* __restrict__ deg,
                                                   float* __restrict__ dinv, int n) {
    int i = blockIdx.x * 256 + threadIdx.x;
    if (i < n) dinv[i] = rsqrtf((float)deg[i] + 1.0f);
}

__global__ __launch_bounds__(256) void scanA_kernel(const unsigned int* __restrict__ deg,
                                                    int n, unsigned int* __restrict__ totals) {
    __shared__ unsigned int s[256];
    int t = threadIdx.x;
    int base = blockIdx.x * 1024 + t * 4;
    unsigned int sum = 0;
#pragma unroll
    for (int k = 0; k < 4; ++k) { int i = base + k; if (i < n) sum += deg[i]; }
    s[t] = sum; __syncthreads();
    for (int off = 128; off > 0; off >>= 1) {
        if (t < off) s[t] += s[t + off];
        __syncthreads();
    }
    if (t == 0) totals[blockIdx.x] = s[0];
}

__global__ __launch_bounds__(128) void scanB_kernel(const unsigned int* __restrict__ totals,
                                                    int nblk, unsigned int* __restrict__ offsets,
                                                    int* __restrict__ row_start, int n, int E) {
    __shared__ unsigned int s[128];
    int t = threadIdx.x;
    unsigned int v = (t < nblk) ? totals[t] : 0u;
    s[t] = v; __syncthreads();
    for (int off = 1; off < 128; off <<= 1) {
        unsigned int x = s[t];
        unsigned int y = (t >= off) ? s[t - off] : 0u;
        __syncthreads();
        s[t] = x + y;
        __syncthreads();
    }
    if (t < nblk) offsets[t] = s[t] - v;
    if (t == 0) row_start[n] = E;
}

__global__ __launch_bounds__(256) void scanC_kernel(const unsigned int* __restrict__ deg,
                                                    const unsigned int* __restrict__ offsets,
                                                    int n, int* __restrict__ row_start,
                                                    int* __restrict__ cursor) {
    __shared__ unsigned int s[256];
    int t = threadIdx.x;
    int base = blockIdx.x * 1024 + t * 4;
    unsigned int v[4];
    unsigned int sum = 0;
#pragma unroll
    for (int k = 0; k < 4; ++k) { int i = base + k; v[k] = (i < n) ? deg[i] : 0u; sum += v[k]; }
    s[t] = sum; __syncthreads();
    for (int off = 1; off < 256; off <<= 1) {
        unsigned int x = s[t];
        unsigned int y = (t >= off) ? s[t - off] : 0u;
        __syncthreads();
        s[t] = x + y;
        __syncthreads();
    }
    unsigned int excl = s[t] - sum + offsets[blockIdx.x];
#pragma unroll
    for (int k = 0; k < 4; ++k) {
        int i = base + k;
        if (i < n) { row_start[i] = (int)excl; cursor[i] = (int)excl; }
        excl += v[k];
    }
}

__global__ __launch_bounds__(256) void fill_kernel(const int* __restrict__ ei, int E,
                                                   const float* __restrict__ dinv,
                                                   int* __restrict__ cursor,
                                                   int2* __restrict__ csr) {
    int e = blockIdx.x * 256 + threadIdx.x;
    if (e >= E) return;
    int s = ei[e];
    int d = ei[E + e];
    int idx = atomicAdd(&cursor[d], 1);
    int2 ent; ent.x = s; ent.y = __float_as_int(dinv[s] * dinv[d]);
    csr[idx] = ent;
}

// ==================== GEMM1: h1[N,64](bf16) = x @ W1 =======================
// Block: 256 threads, 16 rows. W1 (32KB) + x-tile (8KB) in LDS, float4 staged.
__global__ __launch_bounds__(256) void gemm1_kernel(
    const float* __restrict__ x, const float* __restrict__ W,
    unsigned short* __restrict__ h1b, int N) {
    __shared__ float Ws[128 * 64];
    __shared__ float xs[16 * 128];
    int tid = threadIdx.x;
    const float4* W4 = (const float4*)W;
    float4* Ws4 = (float4*)Ws;
#pragma unroll
    for (int i = 0; i < 8; ++i) Ws4[tid + 256 * i] = W4[tid + 256 * i];
    int row0 = blockIdx.x * 16;
    const float4* x4 = (const float4*)(x + (size_t)row0 * 128);
    float4* xs4 = (float4*)xs;
#pragma unroll
    for (int i = 0; i < 2; ++i) xs4[tid + 256 * i] = x4[tid + 256 * i];
    __syncthreads();
    int j = tid & 63;
    int rg = tid >> 6;
    float acc0 = 0.f, acc1 = 0.f, acc2 = 0.f, acc3 = 0.f;
#pragma unroll 8
    for (int k = 0; k < 128; ++k) {
        float w = Ws[k * 64 + j];
        acc0 += xs[(rg + 0) * 128 + k] * w;
        acc1 += xs[(rg + 4) * 128 + k] * w;
        acc2 += xs[(rg + 8) * 128 + k] * w;
        acc3 += xs[(rg + 12) * 128 + k] * w;
    }
    float accs[4] = {acc0, acc1, acc2, acc3};
#pragma unroll
    for (int i = 0; i < 4; ++i) {
        int r = row0 + rg + i * 4;
        h1b[(size_t)r * 64 + j] = f2bf_rn(accs[i]);
    }
}

// ============ Aggregation 1 (+bias+relu) fused with GEMM2 ==================
// 32 lanes per dst node, each lane owns a bf16 feature-PAIR (4B gathers).
// Per edge per node: one 128B coalesced row gather, no atomics.
// Then h_relu row -> LDS, each of the 32 lanes computes one of 32 GEMM2
// outputs (64 MACs vs LDS-broadcast hr + W2s), stores h2 as bf16.
__global__ __launch_bounds__(256) void agg1_kernel(
    const unsigned int* __restrict__ h1u,   // [N,32] bf16-pairs
    const int2* __restrict__ csr,
    const int* __restrict__ row_start, const float* __restrict__ dinv,
    const float* __restrict__ b1, const float* __restrict__ W2,
    unsigned short* __restrict__ h2b, int N) {
    __shared__ float W2s[64 * 32];
    __shared__ float hr[8][64];
    int tid = threadIdx.x;
    const float4* W24 = (const float4*)W2;
    float4* W2s4 = (float4*)W2s;
#pragma unroll
    for (int i = 0; i < 2; ++i) W2s4[tid + 256 * i] = W24[tid + 256 * i];
    __syncthreads();
    int nib = tid >> 5;           // node-in-block 0..7
    int jp = tid & 31;            // feature pair
    int d = blockIdx.x * 8 + nib;
    if (d >= N) return;           // no barriers after this point
    float di = dinv[d];
    float2 bias = ((const float2*)b1)[jp];
    unsigned int su = h1u[(size_t)d * 32 + jp];
    float a0 = bf_lo(su) * di * di;   // self-loop
    float a1 = bf_hi(su) * di * di;
    int beg = row_start[d], end = row_start[d + 1];
    int e = beg;
    for (; e + 1 < end; e += 2) {
        int2 c0 = csr[e], c1 = csr[e + 1];
        unsigned int u0 = h1u[(size_t)c0.x * 32 + jp];
        unsigned int u1 = h1u[(size_t)c1.x * 32 + jp];
        float n0 = __int_as_float(c0.y), n1 = __int_as_float(c1.y);
        a0 += bf_lo(u0) * n0; a1 += bf_hi(u0) * n0;
        a0 += bf_lo(u1) * n1; a1 += bf_hi(u1) * n1;
    }
    if (e < end) {
        int2 c0 = csr[e];
        unsigned int u0 = h1u[(size_t)c0.x * 32 + jp];
        float n0 = __int_as_float(c0.y);
        a0 += bf_lo(u0) * n0; a1 += bf_hi(u0) * n0;
    }
    float h0 = a0 + bias.x; h0 = h0 > 0.f ? h0 : 0.f;
    float h1v = a1 + bias.y; h1v = h1v > 0.f ? h1v : 0.f;
    hr[nib][2 * jp] = h0;                 // intra-wave LDS, no barrier needed
    hr[nib][2 * jp + 1] = h1v;
    // GEMM2: h2[d,c] = sum_k hr[k] * W2[k,c], c = jp
    const float* hrw = hr[nib];
    float p = 0.f;
#pragma unroll 8
    for (int k = 0; k < 64; ++k)
        p += hrw[k] * W2s[k * 32 + jp];
    h2b[(size_t)d * 32 + jp] = f2bf_rn(p);
}

// ===================== Aggregation 2 -> out (final layer) ==================
// 16 lanes per node, bf16 feature-pairs; out fully overwritten (float2 store).
__global__ __launch_bounds__(256) void agg2_kernel(
    const unsigned int* __restrict__ h2u,   // [N,16] bf16-pairs
    const int2* __restrict__ csr,
    const int* __restrict__ row_start, const float* __restrict__ dinv,
    const float* __restrict__ b2, float* __restrict__ out, int N) {
    int tid = blockIdx.x * 256 + threadIdx.x;
    int d = tid >> 4;
    int jp = tid & 15;
    if (d >= N) return;
    float di = dinv[d];
    float2 bias = ((const float2*)b2)[jp];
    unsigned int su = h2u[(size_t)d * 16 + jp];
    float a0 = bf_lo(su) * di * di + bias.x;
    float a1 = bf_hi(su) * di * di + bias.y;
    int beg = row_start[d], end = row_start[d + 1];
    int e = beg;
    for (; e + 1 < end; e += 2) {
        int2 c0 = csr[e], c1 = csr[e + 1];
        unsigned int u0 = h2u[(size_t)c0.x * 16 + jp];
        unsigned int u1 = h2u[(size_t)c1.x * 16 + jp];
        float n0 = __int_as_float(c0.y), n1 = __int_as_float(c1.y);
        a0 += bf_lo(u0) * n0; a1 += bf_hi(u0) * n0;
        a0 += bf_lo(u1) * n1; a1 += bf_hi(u1) * n1;
    }
    if (e < end) {
        int2 c0 = csr[e];
        unsigned int u0 = h2u[(size_t)c0.x * 16 + jp];
        float n0 = __int_as_float(c0.y);
        a0 += bf_lo(u0) * n0; a1 += bf_hi(u0) * n0;
    }
    float2 r; r.x = a0; r.y = a1;
    ((float2*)(out + (size_t)d * 32))[jp] = r;
}

extern "C" void kernel_launch(void* const* d_in, const int* in_sizes, int n_in,
                              void* d_out, int out_size, void* d_ws, size_t ws_size,
                              hipStream_t stream) {
    const float* x  = (const float*)d_in[0];
    const int*   ei = (const int*)d_in[1];
    const float* W1 = (const float*)d_in[2];
    const float* b1 = (const float*)d_in[3];
    const float* W2 = (const float*)d_in[4];
    const float* b2 = (const float*)d_in[5];
    float* out = (float*)d_out;

    const int N = N_NODES;
    const int E = in_sizes[1] / 2;
    const int NBLK = (N + 1023) / 1024;  // 98

    // Workspace: csr[E]i2 | h1b[N*64]bf16 | h2b[N*32]bf16 | deg | dinv |
    // row_start[N+1] | cursor[N] | totals | offsets   (~33 MB)
    char* p = (char*)d_ws;
    int2* csr = (int2*)p;                     p += (size_t)E * 8;
    unsigned short* h1b = (unsigned short*)p; p += (size_t)N * 64 * 2;
    unsigned short* h2b = (unsigned short*)p; p += (size_t)N * 32 * 2;
    unsigned int* deg = (unsigned int*)p;     p += (size_t)N * 4;
    float* dinv = (float*)p;                  p += (size_t)N * 4;
    int* row_start = (int*)p;                 p += (size_t)(N + 1) * 4;
    int* cursor = (int*)p;                    p += (size_t)N * 4;
    unsigned int* totals = (unsigned int*)p;  p += 128 * 4;
    unsigned int* offsets = (unsigned int*)p;

    hipMemsetAsync(deg, 0, (size_t)N * sizeof(unsigned int), stream);

    hist_kernel<<<(E + 255) / 256, 256, 0, stream>>>(ei + E, E, deg);
    dinv_kernel<<<(N + 255) / 256, 256, 0, stream>>>(deg, dinv, N);
    scanA_kernel<<<NBLK, 256, 0, stream>>>(deg, N, totals);
    scanB_kernel<<<1, 128, 0, stream>>>(totals, NBLK, offsets, row_start, N, E);
    scanC_kernel<<<NBLK, 256, 0, stream>>>(deg, offsets, N, row_start, cursor);
    fill_kernel<<<(E + 255) / 256, 256, 0, stream>>>(ei, E, dinv, cursor, csr);

    gemm1_kernel<<<N / 16, 256, 0, stream>>>(x, W1, h1b, N);
    agg1_kernel<<<(N + 7) / 8, 256, 0, stream>>>((const unsigned int*)h1b, csr, row_start,
                                                 dinv, b1, W2, h2b, N);
    agg2_kernel<<<(N * 16 + 255) / 256, 256, 0, stream>>>((const unsigned int*)h2b, csr,
                                                          row_start, dinv, b2, out, N);
}

// Round 4
// 353.026 us; speedup vs baseline: 2.1854x; 1.0757x over previous
//
#include <hip/hip_runtime.h>

#define N_NODES 100000

// ---- bf16 helpers (manual, RNE) -------------------------------------------
__device__ __forceinline__ unsigned short f2bf_rn(float f) {
    unsigned int b = __float_as_uint(f);
    b += 0x7fffu + ((b >> 16) & 1u);
    return (unsigned short)(b >> 16);
}
__device__ __forceinline__ float bf_lo(unsigned int u) { return __uint_as_float(u << 16); }
__device__ __forceinline__ float bf_hi(unsigned int u) { return __uint_as_float(u & 0xffff0000u); }

// ============================ degree + dinv ================================

__global__ __launch_bounds__(256) void hist_kernel(const int* __restrict__ dst, int E,
                                                   unsigned int* __restrict__ deg) {
    int i = blockIdx.x * 256 + threadIdx.x;
    if (i < E) atomicAdd(&deg[dst[i]], 1u);
}

__global__ __launch_bounds__(256) void dinv_kernel(const unsigned int* __restrict__ deg,
                                                   float* __restrict__ dinv, int n) {
    int i = blockIdx.x * 256 + threadIdx.x;
    if (i < n) dinv[i] = rsqrtf((float)deg[i] + 1.0f);
}

// ======================= row_start = exclusive scan(deg) ===================

__global__ __launch_bounds__(256) void scanA_kernel(const unsigned int* __restrict__ deg,
                                                    int n, unsigned int* __restrict__ totals) {
    __shared__ unsigned int s[256];
    int t = threadIdx.x;
    int base = blockIdx.x * 1024 + t * 4;
    unsigned int sum = 0;
#pragma unroll
    for (int k = 0; k < 4; ++k) { int i = base + k; if (i < n) sum += deg[i]; }
    s[t] = sum; __syncthreads();
    for (int off = 128; off > 0; off >>= 1) {
        if (t < off) s[t] += s[t + off];
        __syncthreads();
    }
    if (t == 0) totals[blockIdx.x] = s[0];
}

__global__ __launch_bounds__(128) void scanB_kernel(const unsigned int* __restrict__ totals,
                                                    int nblk, unsigned int* __restrict__ offsets,
                                                    int* __restrict__ row_start, int n, int E) {
    __shared__ unsigned int s[128];
    int t = threadIdx.x;
    unsigned int v = (t < nblk) ? totals[t] : 0u;
    s[t] = v; __syncthreads();
    for (int off = 1; off < 128; off <<= 1) {
        unsigned int x = s[t];
        unsigned int y = (t >= off) ? s[t - off] : 0u;
        __syncthreads();
        s[t] = x + y;
        __syncthreads();
    }
    if (t < nblk) offsets[t] = s[t] - v;
    if (t == 0) row_start[n] = E;
}

__global__ __launch_bounds__(256) void scanC_kernel(const unsigned int* __restrict__ deg,
                                                    const unsigned int* __restrict__ offsets,
                                                    int n, int* __restrict__ row_start) {
    __shared__ unsigned int s[256];
    int t = threadIdx.x;
    int base = blockIdx.x * 1024 + t * 4;
    unsigned int v[4];
    unsigned int sum = 0;
#pragma unroll
    for (int k = 0; k < 4; ++k) { int i = base + k; v[k] = (i < n) ? deg[i] : 0u; sum += v[k]; }
    s[t] = sum; __syncthreads();
    for (int off = 1; off < 256; off <<= 1) {
        unsigned int x = s[t];
        unsigned int y = (t >= off) ? s[t - off] : 0u;
        __syncthreads();
        s[t] = x + y;
        __syncthreads();
    }
    unsigned int excl = s[t] - sum + offsets[blockIdx.x];
#pragma unroll
    for (int k = 0; k < 4; ++k) {
        int i = base + k;
        if (i < n) row_start[i] = (int)excl;
        excl += v[k];
    }
}

// bucket_cursor[b] = row_start[b*512]  (bucket base in edge space)
__global__ __launch_bounds__(256) void bcur_kernel(const int* __restrict__ row_start,
                                                   unsigned int* __restrict__ bucket_cursor,
                                                   int nb) {
    int t = threadIdx.x;
    if (t < nb) bucket_cursor[t] = (unsigned int)row_start[t << 9];
}

// =================== bin: group edges by 512-node bucket ===================
// Block = 4096 edges. LDS count per bucket -> one global atomic per
// (block,bucket) reserves a contiguous run -> packed 4B entries written via
// LDS cursors. Entry: src (17b) | dst&511 (9b)<<17.
__global__ __launch_bounds__(256) void bin_kernel(const int* __restrict__ ei, int E,
                                                  unsigned int* __restrict__ bucket_cursor,
                                                  unsigned int* __restrict__ binned) {
    __shared__ unsigned int cnt[256];
    __shared__ unsigned int cur[256];
    int t = threadIdx.x;
    cnt[t] = 0;
    __syncthreads();
    int base = blockIdx.x * 4096;
    unsigned int pk[16];
    unsigned int bk[16];
#pragma unroll
    for (int k = 0; k < 16; ++k) {
        int e = base + k * 256 + t;
        if (e < E) {
            int s = ei[e];
            int d = ei[E + e];
            unsigned int b = (unsigned int)d >> 9;
            pk[k] = (unsigned int)s | (((unsigned int)d & 511u) << 17);
            bk[k] = b;
            atomicAdd(&cnt[b], 1u);
        } else {
            bk[k] = 0xFFFFFFFFu;
        }
    }
    __syncthreads();
    if (cnt[t] > 0) cur[t] = atomicAdd(&bucket_cursor[t], cnt[t]);
    __syncthreads();
#pragma unroll
    for (int k = 0; k < 16; ++k) {
        if (bk[k] != 0xFFFFFFFFu) {
            unsigned int pos = atomicAdd(&cur[bk[k]], 1u);
            binned[pos] = pk[k];
        }
    }
}

// ============ place: one block per bucket -> final CSR (src, norm) =========
// Block owns nodes [b*512, b*512+512): LDS cursors from row_start, dense read
// of its binned range, writes confined to a 64KB single-XCD window.
__global__ __launch_bounds__(1024) void place_kernel(const unsigned int* __restrict__ binned,
                                                     const int* __restrict__ row_start,
                                                     const float* __restrict__ dinv,
                                                     int2* __restrict__ csr, int N) {
    __shared__ int cur[512];
    __shared__ float dv[512];
    int t = threadIdx.x;
    int node0 = blockIdx.x << 9;
    if (t < 512) {
        int idx = node0 + t;
        int g = idx < N ? idx : N;
        cur[t] = row_start[g];
        dv[t] = dinv[idx < N ? idx : (N - 1)];
    }
    int endn = node0 + 512; if (endn > N) endn = N;
    int beg = row_start[node0];
    int end = row_start[endn];
    __syncthreads();
    for (int i = beg + t; i < end; i += 1024) {
        unsigned int u = binned[i];
        int s = (int)(u & 0x1FFFFu);
        int doff = (int)(u >> 17);
        int slot = atomicAdd(&cur[doff], 1);
        int2 ent; ent.x = s; ent.y = __float_as_int(dinv[s] * dv[doff]);
        csr[slot] = ent;
    }
}

// ==================== GEMM1: h1[N,64](bf16) = x @ W1 =======================
__global__ __launch_bounds__(256) void gemm1_kernel(
    const float* __restrict__ x, const float* __restrict__ W,
    unsigned short* __restrict__ h1b, int N) {
    __shared__ float Ws[128 * 64];
    __shared__ float xs[16 * 128];
    int tid = threadIdx.x;
    const float4* W4 = (const float4*)W;
    float4* Ws4 = (float4*)Ws;
#pragma unroll
    for (int i = 0; i < 8; ++i) Ws4[tid + 256 * i] = W4[tid + 256 * i];
    int row0 = blockIdx.x * 16;
    const float4* x4 = (const float4*)(x + (size_t)row0 * 128);
    float4* xs4 = (float4*)xs;
#pragma unroll
    for (int i = 0; i < 2; ++i) xs4[tid + 256 * i] = x4[tid + 256 * i];
    __syncthreads();
    int j = tid & 63;
    int rg = tid >> 6;
    float acc0 = 0.f, acc1 = 0.f, acc2 = 0.f, acc3 = 0.f;
#pragma unroll 8
    for (int k = 0; k < 128; ++k) {
        float w = Ws[k * 64 + j];
        acc0 += xs[(rg + 0) * 128 + k] * w;
        acc1 += xs[(rg + 4) * 128 + k] * w;
        acc2 += xs[(rg + 8) * 128 + k] * w;
        acc3 += xs[(rg + 12) * 128 + k] * w;
    }
    float accs[4] = {acc0, acc1, acc2, acc3};
#pragma unroll
    for (int i = 0; i < 4; ++i) {
        int r = row0 + rg + i * 4;
        h1b[(size_t)r * 64 + j] = f2bf_rn(accs[i]);
    }
}

// ============ Aggregation 1 (+bias+relu) fused with GEMM2 ==================
__global__ __launch_bounds__(256) void agg1_kernel(
    const unsigned int* __restrict__ h1u,   // [N,32] bf16-pairs
    const int2* __restrict__ csr,
    const int* __restrict__ row_start, const float* __restrict__ dinv,
    const float* __restrict__ b1, const float* __restrict__ W2,
    unsigned short* __restrict__ h2b, int N) {
    __shared__ float W2s[64 * 32];
    __shared__ float hr[8][64];
    int tid = threadIdx.x;
    const float4* W24 = (const float4*)W2;
    float4* W2s4 = (float4*)W2s;
#pragma unroll
    for (int i = 0; i < 2; ++i) W2s4[tid + 256 * i] = W24[tid + 256 * i];
    __syncthreads();
    int nib = tid >> 5;
    int jp = tid & 31;
    int d = blockIdx.x * 8 + nib;
    if (d >= N) return;  // no barriers after this point
    float di = dinv[d];
    float2 bias = ((const float2*)b1)[jp];
    unsigned int su = h1u[(size_t)d * 32 + jp];
    float a0 = bf_lo(su) * di * di;
    float a1 = bf_hi(su) * di * di;
    int beg = row_start[d], end = row_start[d + 1];
    int e = beg;
    for (; e + 1 < end; e += 2) {
        int2 c0 = csr[e], c1 = csr[e + 1];
        unsigned int u0 = h1u[(size_t)c0.x * 32 + jp];
        unsigned int u1 = h1u[(size_t)c1.x * 32 + jp];
        float n0 = __int_as_float(c0.y), n1 = __int_as_float(c1.y);
        a0 += bf_lo(u0) * n0; a1 += bf_hi(u0) * n0;
        a0 += bf_lo(u1) * n1; a1 += bf_hi(u1) * n1;
    }
    if (e < end) {
        int2 c0 = csr[e];
        unsigned int u0 = h1u[(size_t)c0.x * 32 + jp];
        float n0 = __int_as_float(c0.y);
        a0 += bf_lo(u0) * n0; a1 += bf_hi(u0) * n0;
    }
    float h0 = a0 + bias.x; h0 = h0 > 0.f ? h0 : 0.f;
    float h1v = a1 + bias.y; h1v = h1v > 0.f ? h1v : 0.f;
    hr[nib][2 * jp] = h0;
    hr[nib][2 * jp + 1] = h1v;
    const float* hrw = hr[nib];
    float p = 0.f;
#pragma unroll 8
    for (int k = 0; k < 64; ++k)
        p += hrw[k] * W2s[k * 32 + jp];
    h2b[(size_t)d * 32 + jp] = f2bf_rn(p);
}

// ===================== Aggregation 2 -> out (final layer) ==================
__global__ __launch_bounds__(256) void agg2_kernel(
    const unsigned int* __restrict__ h2u,   // [N,16] bf16-pairs
    const int2* __restrict__ csr,
    const int* __restrict__ row_start, const float* __restrict__ dinv,
    const float* __restrict__ b2, float* __restrict__ out, int N) {
    int tid = blockIdx.x * 256 + threadIdx.x;
    int d = tid >> 4;
    int jp = tid & 15;
    if (d >= N) return;
    float di = dinv[d];
    float2 bias = ((const float2*)b2)[jp];
    unsigned int su = h2u[(size_t)d * 16 + jp];
    float a0 = bf_lo(su) * di * di + bias.x;
    float a1 = bf_hi(su) * di * di + bias.y;
    int beg = row_start[d], end = row_start[d + 1];
    int e = beg;
    for (; e + 1 < end; e += 2) {
        int2 c0 = csr[e], c1 = csr[e + 1];
        unsigned int u0 = h2u[(size_t)c0.x * 16 + jp];
        unsigned int u1 = h2u[(size_t)c1.x * 16 + jp];
        float n0 = __int_as_float(c0.y), n1 = __int_as_float(c1.y);
        a0 += bf_lo(u0) * n0; a1 += bf_hi(u0) * n0;
        a0 += bf_lo(u1) * n1; a1 += bf_hi(u1) * n1;
    }
    if (e < end) {
        int2 c0 = csr[e];
        unsigned int u0 = h2u[(size_t)c0.x * 16 + jp];
        float n0 = __int_as_float(c0.y);
        a0 += bf_lo(u0) * n0; a1 += bf_hi(u0) * n0;
    }
    float2 r; r.x = a0; r.y = a1;
    ((float2*)(out + (size_t)d * 32))[jp] = r;
}

extern "C" void kernel_launch(void* const* d_in, const int* in_sizes, int n_in,
                              void* d_out, int out_size, void* d_ws, size_t ws_size,
                              hipStream_t stream) {
    const float* x  = (const float*)d_in[0];
    const int*   ei = (const int*)d_in[1];
    const float* W1 = (const float*)d_in[2];
    const float* b1 = (const float*)d_in[3];
    const float* W2 = (const float*)d_in[4];
    const float* b2 = (const float*)d_in[5];
    float* out = (float*)d_out;

    const int N = N_NODES;
    const int E = in_sizes[1] / 2;
    const int NBLK = (N + 1023) / 1024;     // 98 scan chunks
    const int NB = (N + 511) / 512;          // 196 buckets

    // Workspace: csr[E]i2 | binned[E]u32 | h1b | h2b | deg | dinv |
    // row_start[N+1] | bucket_cursor[256] | totals | offsets  (~40 MB)
    char* p = (char*)d_ws;
    int2* csr = (int2*)p;                     p += (size_t)E * 8;
    unsigned int* binned = (unsigned int*)p;  p += (size_t)E * 4;
    unsigned short* h1b = (unsigned short*)p; p += (size_t)N * 64 * 2;
    unsigned short* h2b = (unsigned short*)p; p += (size_t)N * 32 * 2;
    unsigned int* deg = (unsigned int*)p;     p += (size_t)N * 4;
    float* dinv = (float*)p;                  p += (size_t)N * 4;
    int* row_start = (int*)p;                 p += (size_t)(N + 1) * 4;
    unsigned int* bucket_cursor = (unsigned int*)p; p += 256 * 4;
    unsigned int* totals = (unsigned int*)p;  p += 128 * 4;
    unsigned int* offsets = (unsigned int*)p;

    hipMemsetAsync(deg, 0, (size_t)N * sizeof(unsigned int), stream);

    hist_kernel<<<(E + 255) / 256, 256, 0, stream>>>(ei + E, E, deg);
    dinv_kernel<<<(N + 255) / 256, 256, 0, stream>>>(deg, dinv, N);
    scanA_kernel<<<NBLK, 256, 0, stream>>>(deg, N, totals);
    scanB_kernel<<<1, 128, 0, stream>>>(totals, NBLK, offsets, row_start, N, E);
    scanC_kernel<<<NBLK, 256, 0, stream>>>(deg, offsets, N, row_start);
    bcur_kernel<<<1, 256, 0, stream>>>(row_start, bucket_cursor, NB);
    bin_kernel<<<(E + 4095) / 4096, 256, 0, stream>>>(ei, E, bucket_cursor, binned);
    place_kernel<<<NB, 1024, 0, stream>>>(binned, row_start, dinv, csr, N);

    gemm1_kernel<<<N / 16, 256, 0, stream>>>(x, W1, h1b, N);
    agg1_kernel<<<(N + 7) / 8, 256, 0, stream>>>((const unsigned int*)h1b, csr, row_start,
                                                 dinv, b1, W2, h2b, N);
    agg2_kernel<<<(N * 16 + 255) / 256, 256, 0, stream>>>((const unsigned int*)h2b, csr,
                                                          row_start, dinv, b2, out, N);
}